// Round 1
// baseline (6093.163 us; speedup 1.0000x reference)
//
#include <hip/hip_runtime.h>
#include <cstdint>
#include <cstddef>

// Problem constants (fixed by the reference)
#define NATOMS 400000
#define NEDGES 1600000
#define NGRAPH 4096
#define F_INN  78
#define HDIM   128
#define FF0D   256
#define FF1D   128

// ---------------- degree / dinv ----------------
__global__ __launch_bounds__(256) void k_deg(const int* __restrict__ dst,
                                             float* __restrict__ deg, int E) {
    int e = blockIdx.x * 256 + threadIdx.x;
    if (e < E) unsafeAtomicAdd(&deg[dst[e]], 1.0f);
}

__global__ __launch_bounds__(256) void k_dinv(float* __restrict__ deg, int n) {
    int i = blockIdx.x * 256 + threadIdx.x;
    if (i < n) deg[i] = rsqrtf(deg[i] + 1.0f);
}

// ---------------- generic register-blocked f32 GEMM ----------------
// out0[M,NC] = f(in[M,K] @ W[K,NC])
// IN_RELU_BIAS: stage relu(in + in_bias[k]) instead of in  (fuses previous layer's bias+relu)
// DUAL:         also write out1 = acc * dinv[row]^2        (self-loop init of agg buffer)
// OUT_RELU_BIAS: out0 = relu(acc + out_bias[col])
template<int K, int NC, bool IN_RELU_BIAS, bool DUAL, bool OUT_RELU_BIAS>
__global__ __launch_bounds__(256) void k_gemm(
    const float* __restrict__ in,
    const float* __restrict__ W,
    const float* __restrict__ in_bias,
    const float* __restrict__ out_bias,
    const float* __restrict__ dinv,
    float* __restrict__ out0,
    float* __restrict__ out1,
    int M)
{
    constexpr int BK = 32;
    constexpr int TC = NC / 8;        // thread cols (threads along col dim)
    constexpr int TR = 256 / TC;      // thread rows
    constexpr int ROWS = TR * 8;      // rows per block tile
    constexpr int XST = ROWS + 4;     // pad keeps 16B alignment & breaks bank conflicts
    constexpr bool VEC = (K % 4 == 0);

    __shared__ float xs[BK][XST];     // transposed A chunk: xs[k][r]
    __shared__ float ws[BK][NC];      // B chunk

    const int tid = threadIdx.x;
    const int tc  = tid % TC;
    const int tr  = tid / TC;
    const int row0 = blockIdx.x * ROWS;

    float acc[8][8];
    #pragma unroll
    for (int i = 0; i < 8; ++i)
        #pragma unroll
        for (int j = 0; j < 8; ++j) acc[i][j] = 0.f;

    for (int k0 = 0; k0 < K; k0 += BK) {
        const bool full = (k0 + BK <= K);
        // ---- stage W chunk (row-major, float4) ----
        {
            constexpr int TASKS = BK * NC / 4;
            #pragma unroll
            for (int it = 0; it < TASKS / 256; ++it) {
                int t  = it * 256 + tid;
                int wk = t / (NC / 4);
                int wc = (t % (NC / 4)) * 4;
                float4 v;
                if (full || (k0 + wk) < K)
                    v = *(const float4*)(W + (size_t)(k0 + wk) * NC + wc);
                else
                    v = make_float4(0.f, 0.f, 0.f, 0.f);
                *(float4*)(&ws[wk][wc]) = v;
            }
        }
        // ---- stage A chunk transposed ----
        {
            constexpr int TASKS = ROWS * BK / 4;
            #pragma unroll
            for (int it = 0; it < TASKS / 256; ++it) {
                int t   = it * 256 + tid;
                int r   = t / (BK / 4);
                int kq  = (t % (BK / 4)) * 4;
                int row = row0 + r;
                float v[4];
                if (VEC && full) {
                    float4 x4 = *(const float4*)(in + (size_t)row * K + k0 + kq);
                    if constexpr (IN_RELU_BIAS) {
                        const float4 bb = *(const float4*)(in_bias + k0 + kq);
                        x4.x = fmaxf(x4.x + bb.x, 0.f);
                        x4.y = fmaxf(x4.y + bb.y, 0.f);
                        x4.z = fmaxf(x4.z + bb.z, 0.f);
                        x4.w = fmaxf(x4.w + bb.w, 0.f);
                    }
                    v[0] = x4.x; v[1] = x4.y; v[2] = x4.z; v[3] = x4.w;
                } else {
                    #pragma unroll
                    for (int j = 0; j < 4; ++j) {
                        int k = k0 + kq + j;
                        float x = (k < K) ? in[(size_t)row * K + k] : 0.f;
                        if constexpr (IN_RELU_BIAS) {
                            if (k < K) x = fmaxf(x + in_bias[k], 0.f);
                        }
                        v[j] = x;
                    }
                }
                #pragma unroll
                for (int j = 0; j < 4; ++j) xs[kq + j][r] = v[j];
            }
        }
        __syncthreads();
        // ---- compute ----
        #pragma unroll 8
        for (int kk = 0; kk < BK; ++kk) {
            float a[8], b[8];
            #pragma unroll
            for (int i = 0; i < 8; ++i) a[i] = xs[kk][tr * 8 + i];
            #pragma unroll
            for (int j = 0; j < 8; ++j) b[j] = ws[kk][tc * 8 + j];
            #pragma unroll
            for (int i = 0; i < 8; ++i)
                #pragma unroll
                for (int j = 0; j < 8; ++j)
                    acc[i][j] = fmaf(a[i], b[j], acc[i][j]);
        }
        __syncthreads();
    }

    // ---- epilogue ----
    #pragma unroll
    for (int i = 0; i < 8; ++i) {
        const int row = row0 + tr * 8 + i;
        if (row < M) {
            float d2 = 0.f;
            if constexpr (DUAL) { float dv = dinv[row]; d2 = dv * dv; }
            #pragma unroll
            for (int jq = 0; jq < 2; ++jq) {
                const int col = tc * 8 + jq * 4;
                float4 v;
                v.x = acc[i][jq * 4 + 0];
                v.y = acc[i][jq * 4 + 1];
                v.z = acc[i][jq * 4 + 2];
                v.w = acc[i][jq * 4 + 3];
                if constexpr (OUT_RELU_BIAS) {
                    const float4 bb = *(const float4*)(out_bias + col);
                    v.x = fmaxf(v.x + bb.x, 0.f);
                    v.y = fmaxf(v.y + bb.y, 0.f);
                    v.z = fmaxf(v.z + bb.z, 0.f);
                    v.w = fmaxf(v.w + bb.w, 0.f);
                }
                *(float4*)(out0 + (size_t)row * NC + col) = v;
                if constexpr (DUAL) {
                    float4 u;
                    u.x = v.x * d2; u.y = v.y * d2; u.z = v.z * d2; u.w = v.w * d2;
                    *(float4*)(out1 + (size_t)row * NC + col) = u;
                }
            }
        }
    }
}

// ---------------- edge scatter: agg[dst] += hw[src] * dinv[src]*dinv[dst] ----------------
// 32 lanes per edge, float4 per lane (128 cols)
__global__ __launch_bounds__(256) void k_scatter(
    const float* __restrict__ hw, float* __restrict__ agg,
    const int* __restrict__ src, const int* __restrict__ dst,
    const float* __restrict__ dinv, int E)
{
    int tid = blockIdx.x * 256 + threadIdx.x;
    int e = tid >> 5;
    if (e >= E) return;
    int c = (tid & 31) * 4;
    int s = src[e], d = dst[e];
    float norm = dinv[s] * dinv[d];
    const float4 v = *(const float4*)(hw + (size_t)s * HDIM + c);
    float* a = agg + (size_t)d * HDIM + c;
    unsafeAtomicAdd(a + 0, v.x * norm);
    unsafeAtomicAdd(a + 1, v.y * norm);
    unsafeAtomicAdd(a + 2, v.z * norm);
    unsafeAtomicAdd(a + 3, v.w * norm);
}

// ---------------- global max pool (batch sorted, segments non-empty) ----------------
// h1 = relu(agg + b1) computed on the fly
__global__ __launch_bounds__(128) void k_pool(
    const float* __restrict__ agg, const float* __restrict__ b1,
    const int* __restrict__ batch, float* __restrict__ out, int Nn)
{
    __shared__ int se[2];
    int g = blockIdx.x;
    if (threadIdx.x < 2) {
        int target = g + (int)threadIdx.x;   // first i with batch[i] >= target
        int lo = 0, hi = Nn;
        while (lo < hi) {
            int mid = (lo + hi) >> 1;
            if (batch[mid] < target) lo = mid + 1; else hi = mid;
        }
        se[threadIdx.x] = lo;
    }
    __syncthreads();
    int start = se[0], end = se[1];
    int c = threadIdx.x;
    float bias = b1[c];
    float m = -1e30f;
    for (int i = start; i < end; ++i) {
        float v = agg[(size_t)i * HDIM + c] + bias;
        v = fmaxf(v, 0.f);
        m = fmaxf(m, v);
    }
    out[(size_t)g * HDIM + c] = m;
}

extern "C" void kernel_launch(void* const* d_in, const int* in_sizes, int n_in,
                              void* d_out, int out_size, void* d_ws, size_t ws_size,
                              hipStream_t stream) {
    const float* x    = (const float*)d_in[0];
    const int*   ei   = (const int*)d_in[1];
    const int*   batch= (const int*)d_in[2];
    const float* W0   = (const float*)d_in[3];
    const float* b0   = (const float*)d_in[4];
    const float* W1   = (const float*)d_in[5];
    const float* b1   = (const float*)d_in[6];
    const float* Wf0  = (const float*)d_in[7];
    const float* bf0  = (const float*)d_in[8];
    const float* Wf1  = (const float*)d_in[9];
    const float* bf1  = (const float*)d_in[10];
    float* out = (float*)d_out;

    const int* srcI = ei;
    const int* dstI = ei + NEDGES;

    // workspace layout
    float* bufA = (float*)d_ws;                               // N*128 (hw)
    float* bufB = bufA + (size_t)NATOMS * HDIM;               // N*128 (agg)
    float* dinv = bufB + (size_t)NATOMS * HDIM;               // N
    float* pool = dinv + NATOMS;                              // G*128
    float* ff0  = pool + (size_t)NGRAPH * HDIM;               // G*256

    // 1) degree -> dinv
    hipMemsetAsync(dinv, 0, (size_t)NATOMS * sizeof(float), stream);
    k_deg <<<(NEDGES + 255) / 256, 256, 0, stream>>>(dstI, dinv, NEDGES);
    k_dinv<<<(NATOMS + 255) / 256, 256, 0, stream>>>(dinv, NATOMS);

    // 2) layer 0: hw0 = x@W0 -> bufA ; bufB = hw0*dinv^2 (self-loop init)
    k_gemm<F_INN, HDIM, false, true, false>
        <<<NATOMS / 128, 256, 0, stream>>>(x, W0, nullptr, nullptr, dinv, bufA, bufB, NATOMS);
    // edge aggregation into bufB
    k_scatter<<<(NEDGES * 32) / 256, 256, 0, stream>>>(bufA, bufB, srcI, dstI, dinv, NEDGES);

    // 3) layer 1: input = relu(bufB + b0) staged on the fly; hw1 -> bufA; bufB = hw1*dinv^2
    //    (bufB alias is safe: each block only reads the rows it later overwrites)
    k_gemm<HDIM, HDIM, true, true, false>
        <<<NATOMS / 128, 256, 0, stream>>>(bufB, W1, b0, nullptr, dinv, bufA, bufB, NATOMS);
    k_scatter<<<(NEDGES * 32) / 256, 256, 0, stream>>>(bufA, bufB, srcI, dstI, dinv, NEDGES);

    // 4) pool: g = segment_max(relu(bufB + b1)) -> pool [G,128]
    k_pool<<<NGRAPH, 128, 0, stream>>>(bufB, b1, batch, pool, NATOMS);

    // 5) FF head
    k_gemm<HDIM, FF0D, false, false, true>
        <<<NGRAPH / 64, 256, 0, stream>>>(pool, Wf0, nullptr, bf0, nullptr, ff0, nullptr, NGRAPH);
    k_gemm<FF0D, FF1D, false, false, true>
        <<<NGRAPH / 128, 256, 0, stream>>>(ff0, Wf1, nullptr, bf1, nullptr, out, nullptr, NGRAPH);
}

// Round 2
// 1188.486 us; speedup vs baseline: 5.1268x; 5.1268x over previous
//
#include <hip/hip_runtime.h>
#include <cstdint>
#include <cstddef>

// Problem constants (fixed by the reference)
#define NATOMS 400000
#define NEDGES 1600000
#define NGRAPH 4096
#define F_INN  78
#define HDIM   128
#define FF0D   256
#define FF1D   128

// ---------------- degree (int) / dinv ----------------
__global__ __launch_bounds__(256) void k_degi(const int* __restrict__ dst,
                                              int* __restrict__ deg, int E) {
    int e = blockIdx.x * 256 + threadIdx.x;
    if (e < E) atomicAdd(&deg[dst[e]], 1);
}

__global__ __launch_bounds__(256) void k_dinv(const int* __restrict__ deg,
                                              float* __restrict__ dinv, int n) {
    int i = blockIdx.x * 256 + threadIdx.x;
    if (i < n) dinv[i] = rsqrtf((float)deg[i] + 1.0f);
}

// ---------------- exclusive scan over N ints (3 kernels, in-place) ----------------
// scan1: per-block (1024 elems) exclusive scan in place, block total -> blockSums
__global__ __launch_bounds__(256) void k_scan1(int* __restrict__ data,
                                               int* __restrict__ blockSums, int n) {
    __shared__ int ts[256];
    const int base = blockIdx.x * 1024 + threadIdx.x * 4;
    int v[4];
    #pragma unroll
    for (int j = 0; j < 4; ++j) v[j] = (base + j < n) ? data[base + j] : 0;
    const int tot = v[0] + v[1] + v[2] + v[3];
    ts[threadIdx.x] = tot;
    __syncthreads();
    #pragma unroll
    for (int off = 1; off < 256; off <<= 1) {
        int t = (threadIdx.x >= off) ? ts[threadIdx.x - off] : 0;
        __syncthreads();
        ts[threadIdx.x] += t;
        __syncthreads();
    }
    int run = ts[threadIdx.x] - tot;   // exclusive prefix of this thread
    #pragma unroll
    for (int j = 0; j < 4; ++j) {
        if (base + j < n) data[base + j] = run;
        run += v[j];
    }
    if (threadIdx.x == 255) blockSums[blockIdx.x] = ts[255];
}

// scan2: single block, exclusive scan of block sums (nb <= 512)
__global__ __launch_bounds__(512) void k_scan2(int* __restrict__ blockSums, int nb) {
    __shared__ int ts[512];
    int v = (threadIdx.x < nb) ? blockSums[threadIdx.x] : 0;
    ts[threadIdx.x] = v;
    __syncthreads();
    #pragma unroll
    for (int off = 1; off < 512; off <<= 1) {
        int t = (threadIdx.x >= off) ? ts[threadIdx.x - off] : 0;
        __syncthreads();
        ts[threadIdx.x] += t;
        __syncthreads();
    }
    if (threadIdx.x < nb) blockSums[threadIdx.x] = ts[threadIdx.x] - v;
}

// scan3: add scanned block offsets; set data[n] = total
__global__ __launch_bounds__(256) void k_scan3(int* __restrict__ data,
                                               const int* __restrict__ blockSums,
                                               int n, int total) {
    const int off = blockSums[blockIdx.x];
    const int base = blockIdx.x * 1024 + threadIdx.x * 4;
    #pragma unroll
    for (int j = 0; j < 4; ++j)
        if (base + j < n) data[base + j] += off;
    if (blockIdx.x == 0 && threadIdx.x == 0) data[n] = total;
}

// ---------------- CSR bucket fill: one int atomic per edge ----------------
__global__ __launch_bounds__(256) void k_fill(const int* __restrict__ src,
                                              const int* __restrict__ dst,
                                              const int* __restrict__ row_start,
                                              int* __restrict__ cursor,
                                              int* __restrict__ csr_src, int E) {
    int e = blockIdx.x * 256 + threadIdx.x;
    if (e >= E) return;
    int d = dst[e];
    int pos = atomicAdd(&cursor[d], 1);
    csr_src[row_start[d] + pos] = src[e];
}

// ---------------- per-node gather aggregation (no f32 atomics) ----------------
// agg[n] = hw[n]*dinv[n]^2 + sum_{s in in(n)} hw[s]*dinv[s]*dinv[n]
// 32 lanes per node (float4/lane covers 128 cols), 8 nodes per block
__global__ __launch_bounds__(256) void k_gather(
    const float* __restrict__ hw, float* __restrict__ agg,
    const int* __restrict__ row_start, const int* __restrict__ csr_src,
    const float* __restrict__ dinv, int Nn)
{
    const int n = blockIdx.x * 8 + (threadIdx.x >> 5);
    const int c = (threadIdx.x & 31) * 4;
    const float dv = dinv[n];
    const float d2 = dv * dv;
    const float4 self = *(const float4*)(hw + (size_t)n * HDIM + c);
    float4 acc;
    acc.x = self.x * d2; acc.y = self.y * d2;
    acc.z = self.z * d2; acc.w = self.w * d2;
    const int s0 = row_start[n], s1 = row_start[n + 1];
    for (int i = s0; i < s1; ++i) {
        const int s = csr_src[i];
        const float norm = dinv[s] * dv;
        const float4 v = *(const float4*)(hw + (size_t)s * HDIM + c);
        acc.x = fmaf(v.x, norm, acc.x);
        acc.y = fmaf(v.y, norm, acc.y);
        acc.z = fmaf(v.z, norm, acc.z);
        acc.w = fmaf(v.w, norm, acc.w);
    }
    *(float4*)(agg + (size_t)n * HDIM + c) = acc;
}

// ---------------- generic register-blocked f32 GEMM ----------------
// out0[M,NC] = f(in[M,K] @ W[K,NC])
// IN_RELU_BIAS: stage relu(in + in_bias[k]) instead of in  (fuses previous layer's bias+relu)
// OUT_RELU_BIAS: out0 = relu(acc + out_bias[col])
template<int K, int NC, bool IN_RELU_BIAS, bool OUT_RELU_BIAS>
__global__ __launch_bounds__(256) void k_gemm(
    const float* __restrict__ in,
    const float* __restrict__ W,
    const float* __restrict__ in_bias,
    const float* __restrict__ out_bias,
    float* __restrict__ out0,
    int M)
{
    constexpr int BK = 32;
    constexpr int TC = NC / 8;        // thread cols
    constexpr int TR = 256 / TC;      // thread rows
    constexpr int ROWS = TR * 8;      // rows per block tile
    constexpr int XST = ROWS + 4;     // pad: 16B alignment + bank-conflict break
    constexpr bool VEC = (K % 4 == 0);

    __shared__ float xs[BK][XST];     // transposed A chunk: xs[k][r]
    __shared__ float ws[BK][NC];      // B chunk

    const int tid = threadIdx.x;
    const int tc  = tid % TC;
    const int tr  = tid / TC;
    const int row0 = blockIdx.x * ROWS;

    float acc[8][8];
    #pragma unroll
    for (int i = 0; i < 8; ++i)
        #pragma unroll
        for (int j = 0; j < 8; ++j) acc[i][j] = 0.f;

    for (int k0 = 0; k0 < K; k0 += BK) {
        const bool full = (k0 + BK <= K);
        // ---- stage W chunk ----
        {
            constexpr int TASKS = BK * NC / 4;
            #pragma unroll
            for (int it = 0; it < TASKS / 256; ++it) {
                int t  = it * 256 + tid;
                int wk = t / (NC / 4);
                int wc = (t % (NC / 4)) * 4;
                float4 v;
                if (full || (k0 + wk) < K)
                    v = *(const float4*)(W + (size_t)(k0 + wk) * NC + wc);
                else
                    v = make_float4(0.f, 0.f, 0.f, 0.f);
                *(float4*)(&ws[wk][wc]) = v;
            }
        }
        // ---- stage A chunk transposed ----
        {
            constexpr int TASKS = ROWS * BK / 4;
            #pragma unroll
            for (int it = 0; it < TASKS / 256; ++it) {
                int t   = it * 256 + tid;
                int r   = t / (BK / 4);
                int kq  = (t % (BK / 4)) * 4;
                int row = row0 + r;
                float v[4];
                if (VEC && full) {
                    float4 x4 = *(const float4*)(in + (size_t)row * K + k0 + kq);
                    if constexpr (IN_RELU_BIAS) {
                        const float4 bb = *(const float4*)(in_bias + k0 + kq);
                        x4.x = fmaxf(x4.x + bb.x, 0.f);
                        x4.y = fmaxf(x4.y + bb.y, 0.f);
                        x4.z = fmaxf(x4.z + bb.z, 0.f);
                        x4.w = fmaxf(x4.w + bb.w, 0.f);
                    }
                    v[0] = x4.x; v[1] = x4.y; v[2] = x4.z; v[3] = x4.w;
                } else {
                    #pragma unroll
                    for (int j = 0; j < 4; ++j) {
                        int k = k0 + kq + j;
                        float x = (k < K) ? in[(size_t)row * K + k] : 0.f;
                        if constexpr (IN_RELU_BIAS) {
                            if (k < K) x = fmaxf(x + in_bias[k], 0.f);
                        }
                        v[j] = x;
                    }
                }
                #pragma unroll
                for (int j = 0; j < 4; ++j) xs[kq + j][r] = v[j];
            }
        }
        __syncthreads();
        // ---- compute ----
        #pragma unroll 8
        for (int kk = 0; kk < BK; ++kk) {
            float a[8], b[8];
            #pragma unroll
            for (int i = 0; i < 8; ++i) a[i] = xs[kk][tr * 8 + i];
            #pragma unroll
            for (int j = 0; j < 8; ++j) b[j] = ws[kk][tc * 8 + j];
            #pragma unroll
            for (int i = 0; i < 8; ++i)
                #pragma unroll
                for (int j = 0; j < 8; ++j)
                    acc[i][j] = fmaf(a[i], b[j], acc[i][j]);
        }
        __syncthreads();
    }

    // ---- epilogue ----
    #pragma unroll
    for (int i = 0; i < 8; ++i) {
        const int row = row0 + tr * 8 + i;
        if (row < M) {
            #pragma unroll
            for (int jq = 0; jq < 2; ++jq) {
                const int col = tc * 8 + jq * 4;
                float4 v;
                v.x = acc[i][jq * 4 + 0];
                v.y = acc[i][jq * 4 + 1];
                v.z = acc[i][jq * 4 + 2];
                v.w = acc[i][jq * 4 + 3];
                if constexpr (OUT_RELU_BIAS) {
                    const float4 bb = *(const float4*)(out_bias + col);
                    v.x = fmaxf(v.x + bb.x, 0.f);
                    v.y = fmaxf(v.y + bb.y, 0.f);
                    v.z = fmaxf(v.z + bb.z, 0.f);
                    v.w = fmaxf(v.w + bb.w, 0.f);
                }
                *(float4*)(out0 + (size_t)row * NC + col) = v;
            }
        }
    }
}

// ---------------- global max pool (batch sorted, segments non-empty) ----------------
__global__ __launch_bounds__(128) void k_pool(
    const float* __restrict__ agg, const float* __restrict__ b1,
    const int* __restrict__ batch, float* __restrict__ out, int Nn)
{
    __shared__ int se[2];
    int g = blockIdx.x;
    if (threadIdx.x < 2) {
        int target = g + (int)threadIdx.x;   // first i with batch[i] >= target
        int lo = 0, hi = Nn;
        while (lo < hi) {
            int mid = (lo + hi) >> 1;
            if (batch[mid] < target) lo = mid + 1; else hi = mid;
        }
        se[threadIdx.x] = lo;
    }
    __syncthreads();
    int start = se[0], end = se[1];
    int c = threadIdx.x;
    float bias = b1[c];
    float m = -1e30f;
    for (int i = start; i < end; ++i) {
        float v = agg[(size_t)i * HDIM + c] + bias;
        v = fmaxf(v, 0.f);
        m = fmaxf(m, v);
    }
    out[(size_t)g * HDIM + c] = m;
}

extern "C" void kernel_launch(void* const* d_in, const int* in_sizes, int n_in,
                              void* d_out, int out_size, void* d_ws, size_t ws_size,
                              hipStream_t stream) {
    const float* x    = (const float*)d_in[0];
    const int*   ei   = (const int*)d_in[1];
    const int*   batch= (const int*)d_in[2];
    const float* W0   = (const float*)d_in[3];
    const float* b0   = (const float*)d_in[4];
    const float* W1   = (const float*)d_in[5];
    const float* b1   = (const float*)d_in[6];
    const float* Wf0  = (const float*)d_in[7];
    const float* bf0  = (const float*)d_in[8];
    const float* Wf1  = (const float*)d_in[9];
    const float* bf1  = (const float*)d_in[10];
    float* out = (float*)d_out;

    const int* srcI = ei;
    const int* dstI = ei + NEDGES;

    constexpr int SCAN_NBLK = (NATOMS + 1023) / 1024;   // 391

    // workspace layout (bytes accounted; aliasing: cursor/blockSums dead before pool/ff0)
    float* bufA      = (float*)d_ws;                          // N*128 f32 (hw)
    float* bufB      = bufA + (size_t)NATOMS * HDIM;          // N*128 f32 (agg)
    float* dinv      = bufB + (size_t)NATOMS * HDIM;          // N f32
    int*   row_start = (int*)(dinv + NATOMS);                 // N+1 ints (doubles as deg)
    int*   csr_src   = row_start + (NATOMS + 1);              // E ints
    int*   cursor    = csr_src + NEDGES;                      // N ints
    int*   blockSums = cursor + NATOMS;                       // 512 ints
    float* pool      = (float*)(blockSums + 512);             // G*128
    float* ff0       = pool + (size_t)NGRAPH * HDIM;          // G*256

    // 1) degree -> dinv ; CSR build (reused for both layers)
    hipMemsetAsync(row_start, 0, (size_t)(NATOMS + 1) * sizeof(int), stream);
    hipMemsetAsync(cursor, 0, (size_t)NATOMS * sizeof(int), stream);
    k_degi<<<(NEDGES + 255) / 256, 256, 0, stream>>>(dstI, row_start, NEDGES);
    k_dinv<<<(NATOMS + 255) / 256, 256, 0, stream>>>(row_start, dinv, NATOMS);
    k_scan1<<<SCAN_NBLK, 256, 0, stream>>>(row_start, blockSums, NATOMS);
    k_scan2<<<1, 512, 0, stream>>>(blockSums, SCAN_NBLK);
    k_scan3<<<SCAN_NBLK, 256, 0, stream>>>(row_start, blockSums, NATOMS, NEDGES);
    k_fill<<<(NEDGES + 255) / 256, 256, 0, stream>>>(srcI, dstI, row_start, cursor, csr_src, NEDGES);

    // 2) layer 0: hw0 = x@W0 -> bufA ; gather-aggregate -> bufB
    k_gemm<F_INN, HDIM, false, false>
        <<<NATOMS / 128, 256, 0, stream>>>(x, W0, nullptr, nullptr, bufA, NATOMS);
    k_gather<<<NATOMS / 8, 256, 0, stream>>>(bufA, bufB, row_start, csr_src, dinv, NATOMS);

    // 3) layer 1: input = relu(bufB + b0) staged on the fly; hw1 -> bufA; gather -> bufB
    k_gemm<HDIM, HDIM, true, false>
        <<<NATOMS / 128, 256, 0, stream>>>(bufB, W1, b0, nullptr, bufA, NATOMS);
    k_gather<<<NATOMS / 8, 256, 0, stream>>>(bufA, bufB, row_start, csr_src, dinv, NATOMS);

    // 4) pool: g = segment_max(relu(bufB + b1)) -> pool [G,128]
    k_pool<<<NGRAPH, 128, 0, stream>>>(bufB, b1, batch, pool, NATOMS);

    // 5) FF head
    k_gemm<HDIM, FF0D, false, true>
        <<<NGRAPH / 64, 256, 0, stream>>>(pool, Wf0, nullptr, bf0, ff0, NGRAPH);
    k_gemm<FF0D, FF1D, false, true>
        <<<NGRAPH / 128, 256, 0, stream>>>(ff0, Wf1, nullptr, bf1, out, NGRAPH);
}

// Round 3
// 844.602 us; speedup vs baseline: 7.2142x; 1.4072x over previous
//
#include <hip/hip_runtime.h>
#include <cstdint>
#include <cstddef>

// Problem constants (fixed by the reference)
#define NATOMS 400000
#define NEDGES 1600000
#define NGRAPH 4096
#define F_INN  78
#define HDIM   128
#define FF0D   256
#define FF1D   128

typedef __attribute__((ext_vector_type(8))) short short8;   // 8 bf16 (4 VGPRs)
typedef __attribute__((ext_vector_type(4))) float f32x4;

// f32 -> bf16 round-to-nearest-even (bit-level, no NaN concerns here)
static __device__ __forceinline__ short f2bf(float f) {
    unsigned u = __builtin_bit_cast(unsigned, f);
    unsigned r = (u + 0x7fffu + ((u >> 16) & 1u)) >> 16;
    return (short)r;
}
static __device__ __forceinline__ float bf2f(unsigned short u) {
    return __builtin_bit_cast(float, ((unsigned)u) << 16);
}

// ---------------- degree (int) / dinv ----------------
__global__ __launch_bounds__(256) void k_degi(const int* __restrict__ dst,
                                              int* __restrict__ deg, int E) {
    int e = blockIdx.x * 256 + threadIdx.x;
    if (e < E) atomicAdd(&deg[dst[e]], 1);
}

__global__ __launch_bounds__(256) void k_dinv(const int* __restrict__ deg,
                                              float* __restrict__ dinv, int n) {
    int i = blockIdx.x * 256 + threadIdx.x;
    if (i < n) dinv[i] = rsqrtf((float)deg[i] + 1.0f);
}

// ---------------- exclusive scan over N ints (3 kernels, in-place) ----------------
__global__ __launch_bounds__(256) void k_scan1(int* __restrict__ data,
                                               int* __restrict__ blockSums, int n) {
    __shared__ int ts[256];
    const int base = blockIdx.x * 1024 + threadIdx.x * 4;
    int v[4];
    #pragma unroll
    for (int j = 0; j < 4; ++j) v[j] = (base + j < n) ? data[base + j] : 0;
    const int tot = v[0] + v[1] + v[2] + v[3];
    ts[threadIdx.x] = tot;
    __syncthreads();
    #pragma unroll
    for (int off = 1; off < 256; off <<= 1) {
        int t = (threadIdx.x >= off) ? ts[threadIdx.x - off] : 0;
        __syncthreads();
        ts[threadIdx.x] += t;
        __syncthreads();
    }
    int run = ts[threadIdx.x] - tot;
    #pragma unroll
    for (int j = 0; j < 4; ++j) {
        if (base + j < n) data[base + j] = run;
        run += v[j];
    }
    if (threadIdx.x == 255) blockSums[blockIdx.x] = ts[255];
}

__global__ __launch_bounds__(512) void k_scan2(int* __restrict__ blockSums, int nb) {
    __shared__ int ts[512];
    int v = (threadIdx.x < nb) ? blockSums[threadIdx.x] : 0;
    ts[threadIdx.x] = v;
    __syncthreads();
    #pragma unroll
    for (int off = 1; off < 512; off <<= 1) {
        int t = (threadIdx.x >= off) ? ts[threadIdx.x - off] : 0;
        __syncthreads();
        ts[threadIdx.x] += t;
        __syncthreads();
    }
    if (threadIdx.x < nb) blockSums[threadIdx.x] = ts[threadIdx.x] - v;
}

__global__ __launch_bounds__(256) void k_scan3(int* __restrict__ data,
                                               const int* __restrict__ blockSums,
                                               int n, int total) {
    const int off = blockSums[blockIdx.x];
    const int base = blockIdx.x * 1024 + threadIdx.x * 4;
    #pragma unroll
    for (int j = 0; j < 4; ++j)
        if (base + j < n) data[base + j] += off;
    if (blockIdx.x == 0 && threadIdx.x == 0) data[n] = total;
}

// ---------------- CSR bucket fill + per-edge norm ----------------
__global__ __launch_bounds__(256) void k_fill(const int* __restrict__ src,
                                              const int* __restrict__ dst,
                                              const int* __restrict__ row_start,
                                              int* __restrict__ cursor,
                                              int* __restrict__ csr_src,
                                              float* __restrict__ csr_norm,
                                              const float* __restrict__ dinv, int E) {
    int e = blockIdx.x * 256 + threadIdx.x;
    if (e >= E) return;
    int d = dst[e];
    int s = src[e];
    int pos = row_start[d] + atomicAdd(&cursor[d], 1);
    csr_src[pos] = s;
    csr_norm[pos] = dinv[s] * dinv[d];
}

// ---------------- weight pack: W [KSRC][128] f32 -> MFMA B-fragment order bf16 ----
// frag f = ct*KC + kc ; lane element j: value = W[kc*32 + (lane>>4)*8 + j][ct*16 + (lane&15)]
template<int KC, int KSRC>
__global__ __launch_bounds__(64) void k_packw(const float* __restrict__ W,
                                              short* __restrict__ wf) {
    int t = blockIdx.x * 64 + threadIdx.x;      // t = f*64 + lane
    int f = t >> 6, lane = t & 63;
    int ct = f / KC, kc = f % KC;
    int n  = ct * 16 + (lane & 15);
    int k0 = kc * 32 + (lane >> 4) * 8;
    short8 o;
    #pragma unroll
    for (int j = 0; j < 8; ++j) {
        int k = k0 + j;
        float v = (k < KSRC) ? W[(size_t)k * 128 + n] : 0.f;
        o[j] = f2bf(v);
    }
    *(short8*)(wf + (size_t)t * 8) = o;
}

// ---------------- MFMA GEMM: out[M,128] = in[M,KSRC] @ W  (bf16 out) ----------------
// No LDS: B-fragments VGPR-resident (pre-packed), A-fragments straight from global.
// Block = 4 waves; each wave: RT row-tiles of 16 rows. Block covers 4*RT*16 rows.
template<int KC, bool F32IN, int KSRC>
__global__ __launch_bounds__(256) void k_gemm_mfma(
    const void* __restrict__ inv, const short* __restrict__ wfrag,
    short* __restrict__ outp, int M)
{
    constexpr int RT = 5;
    const int wid  = threadIdx.x >> 6;
    const int lane = threadIdx.x & 63;
    const int m = lane & 15, q = lane >> 4;
    const int rowbase = blockIdx.x * (4 * RT * 16) + wid * (RT * 16);

    // B fragments, resident for the whole block
    short8 bfr[8 * KC];
    #pragma unroll
    for (int f = 0; f < 8 * KC; ++f)
        bfr[f] = *(const short8*)(wfrag + ((size_t)(f * 64 + lane)) * 8);

    for (int rt = 0; rt < RT; ++rt) {
        const int rowa = rowbase + rt * 16 + m;
        short8 afr[KC];
        if constexpr (F32IN) {
            const float* xr = (const float*)inv + (size_t)rowa * KSRC;
            #pragma unroll
            for (int kc = 0; kc < KC; ++kc) {
                const int k0 = kc * 32 + q * 8;
                float v[8];
                #pragma unroll
                for (int j = 0; j < 8; ++j) v[j] = 0.f;
                if (k0 < KSRC) {
                    #pragma unroll
                    for (int p = 0; p < 4; ++p) {
                        int k = k0 + 2 * p;
                        if (k < KSRC) {       // KSRC even: pairs never straddle
                            float2 t = *(const float2*)(xr + k);
                            v[2 * p] = t.x; v[2 * p + 1] = t.y;
                        }
                    }
                }
                short8 a;
                #pragma unroll
                for (int j = 0; j < 8; ++j) a[j] = f2bf(v[j]);
                afr[kc] = a;
            }
        } else {
            const short* xr = (const short*)inv + (size_t)rowa * KSRC;
            #pragma unroll
            for (int kc = 0; kc < KC; ++kc)
                afr[kc] = *(const short8*)(xr + kc * 32 + q * 8);
        }

        f32x4 acc[8];
        #pragma unroll
        for (int ct = 0; ct < 8; ++ct) acc[ct] = (f32x4){0.f, 0.f, 0.f, 0.f};
        #pragma unroll
        for (int kc = 0; kc < KC; ++kc)
            #pragma unroll
            for (int ct = 0; ct < 8; ++ct)
                acc[ct] = __builtin_amdgcn_mfma_f32_16x16x32_bf16(
                    afr[kc], bfr[ct * KC + kc], acc[ct], 0, 0, 0);

        // C layout: col = lane&15, row = q*4 + reg
        #pragma unroll
        for (int ct = 0; ct < 8; ++ct)
            #pragma unroll
            for (int r = 0; r < 4; ++r) {
                int gr = rowbase + rt * 16 + q * 4 + r;
                outp[(size_t)gr * 128 + ct * 16 + m] = f2bf(acc[ct][r]);
            }
    }
}

// ---------------- gather aggregation, bf16 in/out, fused bias+relu ----------------
// out[n] = relu(bias + hw[n]*dinv[n]^2 + sum_s hw[s]*norm(s,n)), 32 lanes/node
__global__ __launch_bounds__(256) void k_gather_bf(
    const unsigned short* __restrict__ hw, unsigned short* __restrict__ agg,
    const int* __restrict__ row_start, const int* __restrict__ csr_src,
    const float* __restrict__ csr_norm, const float* __restrict__ dinv,
    const float* __restrict__ bias, int Nn)
{
    const int n = blockIdx.x * 8 + (threadIdx.x >> 5);
    const int c = (threadIdx.x & 31) * 4;
    const float dv = dinv[n];
    const float d2 = dv * dv;
    const float4 b = *(const float4*)(bias + c);
    const ushort4 sv = *(const ushort4*)(hw + (size_t)n * HDIM + c);
    float a0 = fmaf(bf2f(sv.x), d2, b.x);
    float a1 = fmaf(bf2f(sv.y), d2, b.y);
    float a2 = fmaf(bf2f(sv.z), d2, b.z);
    float a3 = fmaf(bf2f(sv.w), d2, b.w);
    const int s0 = row_start[n], s1 = row_start[n + 1];
    for (int i = s0; i < s1; ++i) {
        const int s = csr_src[i];
        const float w = csr_norm[i];
        const ushort4 v = *(const ushort4*)(hw + (size_t)s * HDIM + c);
        a0 = fmaf(bf2f(v.x), w, a0);
        a1 = fmaf(bf2f(v.y), w, a1);
        a2 = fmaf(bf2f(v.z), w, a2);
        a3 = fmaf(bf2f(v.w), w, a3);
    }
    ushort4 o;
    o.x = (unsigned short)f2bf(fmaxf(a0, 0.f));
    o.y = (unsigned short)f2bf(fmaxf(a1, 0.f));
    o.z = (unsigned short)f2bf(fmaxf(a2, 0.f));
    o.w = (unsigned short)f2bf(fmaxf(a3, 0.f));
    *(ushort4*)(agg + (size_t)n * HDIM + c) = o;
}

// ---------------- global max pool over bf16 rows (already bias+relu'd) -----------
__global__ __launch_bounds__(128) void k_pool(
    const unsigned short* __restrict__ agg,
    const int* __restrict__ batch, float* __restrict__ out, int Nn)
{
    __shared__ int se[2];
    int g = blockIdx.x;
    if (threadIdx.x < 2) {
        int target = g + (int)threadIdx.x;
        int lo = 0, hi = Nn;
        while (lo < hi) {
            int mid = (lo + hi) >> 1;
            if (batch[mid] < target) lo = mid + 1; else hi = mid;
        }
        se[threadIdx.x] = lo;
    }
    __syncthreads();
    int start = se[0], end = se[1];
    int c = threadIdx.x;
    float m = 0.f;   // values are post-relu, >= 0; segments non-empty
    for (int i = start; i < end; ++i)
        m = fmaxf(m, bf2f(agg[(size_t)i * HDIM + c]));
    out[(size_t)g * HDIM + c] = m;
}

// ---------------- f32 register-blocked GEMM (FF head only, tiny) ----------------
template<int K, int NC, bool OUT_RELU_BIAS>
__global__ __launch_bounds__(256) void k_gemm(
    const float* __restrict__ in, const float* __restrict__ W,
    const float* __restrict__ out_bias, float* __restrict__ out0, int M)
{
    constexpr int BK = 32;
    constexpr int TC = NC / 8;
    constexpr int TR = 256 / TC;
    constexpr int ROWS = TR * 8;
    constexpr int XST = ROWS + 4;

    __shared__ float xs[BK][XST];
    __shared__ float ws[BK][NC];

    const int tid = threadIdx.x;
    const int tc  = tid % TC;
    const int tr  = tid / TC;
    const int row0 = blockIdx.x * ROWS;

    float acc[8][8];
    #pragma unroll
    for (int i = 0; i < 8; ++i)
        #pragma unroll
        for (int j = 0; j < 8; ++j) acc[i][j] = 0.f;

    for (int k0 = 0; k0 < K; k0 += BK) {
        {
            constexpr int TASKS = BK * NC / 4;
            #pragma unroll
            for (int it = 0; it < TASKS / 256; ++it) {
                int t  = it * 256 + tid;
                int wk = t / (NC / 4);
                int wc = (t % (NC / 4)) * 4;
                *(float4*)(&ws[wk][wc]) = *(const float4*)(W + (size_t)(k0 + wk) * NC + wc);
            }
        }
        {
            constexpr int TASKS = ROWS * BK / 4;
            #pragma unroll
            for (int it = 0; it < TASKS / 256; ++it) {
                int t   = it * 256 + tid;
                int r   = t / (BK / 4);
                int kq  = (t % (BK / 4)) * 4;
                float4 x4 = *(const float4*)(in + (size_t)(row0 + r) * K + k0 + kq);
                xs[kq + 0][r] = x4.x; xs[kq + 1][r] = x4.y;
                xs[kq + 2][r] = x4.z; xs[kq + 3][r] = x4.w;
            }
        }
        __syncthreads();
        #pragma unroll 8
        for (int kk = 0; kk < BK; ++kk) {
            float a[8], b[8];
            #pragma unroll
            for (int i = 0; i < 8; ++i) a[i] = xs[kk][tr * 8 + i];
            #pragma unroll
            for (int j = 0; j < 8; ++j) b[j] = ws[kk][tc * 8 + j];
            #pragma unroll
            for (int i = 0; i < 8; ++i)
                #pragma unroll
                for (int j = 0; j < 8; ++j)
                    acc[i][j] = fmaf(a[i], b[j], acc[i][j]);
        }
        __syncthreads();
    }

    #pragma unroll
    for (int i = 0; i < 8; ++i) {
        const int row = row0 + tr * 8 + i;
        #pragma unroll
        for (int jq = 0; jq < 2; ++jq) {
            const int col = tc * 8 + jq * 4;
            float4 v;
            v.x = acc[i][jq * 4 + 0]; v.y = acc[i][jq * 4 + 1];
            v.z = acc[i][jq * 4 + 2]; v.w = acc[i][jq * 4 + 3];
            if constexpr (OUT_RELU_BIAS) {
                const float4 bb = *(const float4*)(out_bias + col);
                v.x = fmaxf(v.x + bb.x, 0.f); v.y = fmaxf(v.y + bb.y, 0.f);
                v.z = fmaxf(v.z + bb.z, 0.f); v.w = fmaxf(v.w + bb.w, 0.f);
            }
            *(float4*)(out0 + (size_t)row * NC + col) = v;
        }
    }
}

extern "C" void kernel_launch(void* const* d_in, const int* in_sizes, int n_in,
                              void* d_out, int out_size, void* d_ws, size_t ws_size,
                              hipStream_t stream) {
    const float* x    = (const float*)d_in[0];
    const int*   ei   = (const int*)d_in[1];
    const int*   batch= (const int*)d_in[2];
    const float* W0   = (const float*)d_in[3];
    const float* b0   = (const float*)d_in[4];
    const float* W1   = (const float*)d_in[5];
    const float* b1   = (const float*)d_in[6];
    const float* Wf0  = (const float*)d_in[7];
    const float* bf0  = (const float*)d_in[8];
    const float* Wf1  = (const float*)d_in[9];
    const float* bf1  = (const float*)d_in[10];
    float* out = (float*)d_out;

    const int* srcI = ei;
    const int* dstI = ei + NEDGES;

    constexpr int SCAN_NBLK = (NATOMS + 1023) / 1024;   // 391

    // workspace layout
    unsigned short* hwA  = (unsigned short*)d_ws;                 // N*128 bf16
    unsigned short* aggB = hwA + (size_t)NATOMS * HDIM;           // N*128 bf16
    float* dinv      = (float*)(aggB + (size_t)NATOMS * HDIM);    // N f32
    int*   row_start = (int*)(dinv + NATOMS);                     // N+1 (doubles as deg)
    int*   csr_src   = row_start + (NATOMS + 1);                  // E
    float* csr_norm  = (float*)(csr_src + NEDGES);                // E
    int*   cursor    = (int*)(csr_norm + NEDGES);                 // N
    int*   blockSums = cursor + NATOMS;                           // 512
    float* pool      = (float*)(blockSums + 512);                 // G*128
    float* ff0       = pool + (size_t)NGRAPH * HDIM;              // G*256
    short* wf0       = (short*)(ff0 + (size_t)NGRAPH * FF0D);     // 8*3*64*8 bf16
    short* wf1       = wf0 + 8 * 3 * 64 * 8;                      // 8*4*64*8 bf16

    // 1) degree -> dinv ; CSR build with per-edge norms
    hipMemsetAsync(row_start, 0, (size_t)(NATOMS + 1) * sizeof(int), stream);
    hipMemsetAsync(cursor, 0, (size_t)NATOMS * sizeof(int), stream);
    k_degi<<<(NEDGES + 255) / 256, 256, 0, stream>>>(dstI, row_start, NEDGES);
    k_dinv<<<(NATOMS + 255) / 256, 256, 0, stream>>>(row_start, dinv, NATOMS);
    k_scan1<<<SCAN_NBLK, 256, 0, stream>>>(row_start, blockSums, NATOMS);
    k_scan2<<<1, 512, 0, stream>>>(blockSums, SCAN_NBLK);
    k_scan3<<<SCAN_NBLK, 256, 0, stream>>>(row_start, blockSums, NATOMS, NEDGES);
    k_fill<<<(NEDGES + 255) / 256, 256, 0, stream>>>(srcI, dstI, row_start, cursor,
                                                     csr_src, csr_norm, dinv, NEDGES);

    // 2) pack weights into MFMA B-fragment order (bf16)
    k_packw<3, F_INN><<<8 * 3, 64, 0, stream>>>(W0, wf0);
    k_packw<4, HDIM><<<8 * 4, 64, 0, stream>>>(W1, wf1);

    // 3) layer 0: hw0 = x@W0 (bf16) ; gather -> relu(agg + b0) bf16
    k_gemm_mfma<3, true, F_INN><<<1250, 256, 0, stream>>>(x, wf0, (short*)hwA, NATOMS);
    k_gather_bf<<<NATOMS / 8, 256, 0, stream>>>(hwA, aggB, row_start, csr_src,
                                                csr_norm, dinv, b0, NATOMS);

    // 4) layer 1: hw1 = h@W1 (bf16) ; gather -> relu(agg + b1) bf16
    k_gemm_mfma<4, false, HDIM><<<1250, 256, 0, stream>>>(aggB, wf1, (short*)hwA, NATOMS);
    k_gather_bf<<<NATOMS / 8, 256, 0, stream>>>(hwA, aggB, row_start, csr_src,
                                                csr_norm, dinv, b1, NATOMS);

    // 5) pool: segment max -> pool f32 [G,128]
    k_pool<<<NGRAPH, 128, 0, stream>>>(aggB, batch, pool, NATOMS);

    // 6) FF head (f32, tiny)
    k_gemm<HDIM, FF0D, true><<<NGRAPH / 64, 256, 0, stream>>>(pool, Wf0, bf0, ff0, NGRAPH);
    k_gemm<FF0D, FF1D, true><<<NGRAPH / 128, 256, 0, stream>>>(ff0, Wf1, bf1, out, NGRAPH);
}

// Round 4
// 779.523 us; speedup vs baseline: 7.8165x; 1.0835x over previous
//
#include <hip/hip_runtime.h>
#include <cstdint>
#include <cstddef>

// Problem constants (fixed by the reference)
#define NATOMS 400000
#define NEDGES 1600000
#define NGRAPH 4096
#define F_INN  78
#define HDIM   128
#define FF0D   256
#define FF1D   128

typedef __attribute__((ext_vector_type(8))) short short8;   // 8 bf16 (4 VGPRs)
typedef __attribute__((ext_vector_type(4))) float f32x4;
typedef __attribute__((ext_vector_type(2))) float f32x2;

// f32 -> bf16 round-to-nearest-even (bit-level)
static __device__ __forceinline__ short f2bf(float f) {
    unsigned u = __builtin_bit_cast(unsigned, f);
    unsigned r = (u + 0x7fffu + ((u >> 16) & 1u)) >> 16;
    return (short)r;
}
static __device__ __forceinline__ float bf2f(unsigned short u) {
    return __builtin_bit_cast(float, ((unsigned)u) << 16);
}

// ---------------- degree (int) / dinv ----------------
__global__ __launch_bounds__(256) void k_degi(const int* __restrict__ dst,
                                              int* __restrict__ deg, int E) {
    int e = blockIdx.x * 256 + threadIdx.x;
    if (e < E) atomicAdd(&deg[dst[e]], 1);
}

__global__ __launch_bounds__(256) void k_dinv(const int* __restrict__ deg,
                                              float* __restrict__ dinv, int n) {
    int i = blockIdx.x * 256 + threadIdx.x;
    if (i < n) dinv[i] = rsqrtf((float)deg[i] + 1.0f);
}

// ---------------- exclusive scan over N ints (3 kernels, in-place) ----------------
__global__ __launch_bounds__(256) void k_scan1(int* __restrict__ data,
                                               int* __restrict__ blockSums, int n) {
    __shared__ int ts[256];
    const int base = blockIdx.x * 1024 + threadIdx.x * 4;
    int v[4];
    #pragma unroll
    for (int j = 0; j < 4; ++j) v[j] = (base + j < n) ? data[base + j] : 0;
    const int tot = v[0] + v[1] + v[2] + v[3];
    ts[threadIdx.x] = tot;
    __syncthreads();
    #pragma unroll
    for (int off = 1; off < 256; off <<= 1) {
        int t = (threadIdx.x >= off) ? ts[threadIdx.x - off] : 0;
        __syncthreads();
        ts[threadIdx.x] += t;
        __syncthreads();
    }
    int run = ts[threadIdx.x] - tot;
    #pragma unroll
    for (int j = 0; j < 4; ++j) {
        if (base + j < n) data[base + j] = run;
        run += v[j];
    }
    if (threadIdx.x == 255) blockSums[blockIdx.x] = ts[255];
}

__global__ __launch_bounds__(512) void k_scan2(int* __restrict__ blockSums, int nb) {
    __shared__ int ts[512];
    int v = (threadIdx.x < nb) ? blockSums[threadIdx.x] : 0;
    ts[threadIdx.x] = v;
    __syncthreads();
    #pragma unroll
    for (int off = 1; off < 512; off <<= 1) {
        int t = (threadIdx.x >= off) ? ts[threadIdx.x - off] : 0;
        __syncthreads();
        ts[threadIdx.x] += t;
        __syncthreads();
    }
    if (threadIdx.x < nb) blockSums[threadIdx.x] = ts[threadIdx.x] - v;
}

// scan3: add block offsets; seed cursor = row_start; set data[n] = total
__global__ __launch_bounds__(256) void k_scan3(int* __restrict__ data,
                                               const int* __restrict__ blockSums,
                                               int* __restrict__ cursor,
                                               int n, int total) {
    const int off = blockSums[blockIdx.x];
    const int base = blockIdx.x * 1024 + threadIdx.x * 4;
    #pragma unroll
    for (int j = 0; j < 4; ++j)
        if (base + j < n) {
            int v = data[base + j] + off;
            data[base + j] = v;
            cursor[base + j] = v;
        }
    if (blockIdx.x == 0 && threadIdx.x == 0) data[n] = total;
}

// ---------------- CSR fill: cursor holds absolute positions; pack (src,norm) ------
__global__ __launch_bounds__(256) void k_fill(const int* __restrict__ src,
                                              const int* __restrict__ dst,
                                              int* __restrict__ cursor,
                                              int2* __restrict__ csr_ev,
                                              const float* __restrict__ dinv, int E) {
    int e = blockIdx.x * 256 + threadIdx.x;
    if (e >= E) return;
    int d = dst[e];
    int s = src[e];
    int pos = atomicAdd(&cursor[d], 1);
    float norm = dinv[s] * dinv[d];
    csr_ev[pos] = make_int2(s, __builtin_bit_cast(int, norm));
}

// ---------------- weight pack: W [KSRC][128] f32 -> MFMA B-fragment order bf16 ----
template<int KC, int KSRC>
__global__ __launch_bounds__(64) void k_packw(const float* __restrict__ W,
                                              short* __restrict__ wf) {
    int t = blockIdx.x * 64 + threadIdx.x;      // t = f*64 + lane
    int f = t >> 6, lane = t & 63;
    int ct = f / KC, kc = f % KC;
    int n  = ct * 16 + (lane & 15);
    int k0 = kc * 32 + (lane >> 4) * 8;
    short8 o;
    #pragma unroll
    for (int j = 0; j < 8; ++j) {
        int k = k0 + j;
        float v = (k < KSRC) ? W[(size_t)k * 128 + n] : 0.f;
        o[j] = f2bf(v);
    }
    *(short8*)(wf + (size_t)t * 8) = o;
}

// ---------------- MFMA GEMM: out[M,128] = in[M,KSRC] @ W  (bf16 out) ----------------
// No LDS: B-fragments VGPR-resident, A straight from global (nt: streamed once).
template<int KC, bool F32IN, int KSRC>
__global__ __launch_bounds__(256) void k_gemm_mfma(
    const void* __restrict__ inv, const short* __restrict__ wfrag,
    short* __restrict__ outp, int M)
{
    constexpr int RT = 5;
    const int wid  = threadIdx.x >> 6;
    const int lane = threadIdx.x & 63;
    const int m = lane & 15, q = lane >> 4;
    const int rowbase = blockIdx.x * (4 * RT * 16) + wid * (RT * 16);

    short8 bfr[8 * KC];
    #pragma unroll
    for (int f = 0; f < 8 * KC; ++f)
        bfr[f] = *(const short8*)(wfrag + ((size_t)(f * 64 + lane)) * 8);

    for (int rt = 0; rt < RT; ++rt) {
        const int rowa = rowbase + rt * 16 + m;
        short8 afr[KC];
        if constexpr (F32IN) {
            const float* xr = (const float*)inv + (size_t)rowa * KSRC;
            #pragma unroll
            for (int kc = 0; kc < KC; ++kc) {
                const int k0 = kc * 32 + q * 8;
                float v[8];
                #pragma unroll
                for (int j = 0; j < 8; ++j) v[j] = 0.f;
                if (k0 < KSRC) {
                    #pragma unroll
                    for (int p = 0; p < 4; ++p) {
                        int k = k0 + 2 * p;
                        if (k < KSRC) {       // KSRC even: pairs never straddle
                            f32x2 t = __builtin_nontemporal_load((const f32x2*)(xr + k));
                            v[2 * p] = t.x; v[2 * p + 1] = t.y;
                        }
                    }
                }
                short8 a;
                #pragma unroll
                for (int j = 0; j < 8; ++j) a[j] = f2bf(v[j]);
                afr[kc] = a;
            }
        } else {
            const short* xr = (const short*)inv + (size_t)rowa * KSRC;
            #pragma unroll
            for (int kc = 0; kc < KC; ++kc)
                afr[kc] = __builtin_nontemporal_load((const short8*)(xr + kc * 32 + q * 8));
        }

        f32x4 acc[8];
        #pragma unroll
        for (int ct = 0; ct < 8; ++ct) acc[ct] = (f32x4){0.f, 0.f, 0.f, 0.f};
        #pragma unroll
        for (int kc = 0; kc < KC; ++kc)
            #pragma unroll
            for (int ct = 0; ct < 8; ++ct)
                acc[ct] = __builtin_amdgcn_mfma_f32_16x16x32_bf16(
                    afr[kc], bfr[ct * KC + kc], acc[ct], 0, 0, 0);

        // C layout: col = lane&15, row = q*4 + reg
        #pragma unroll
        for (int ct = 0; ct < 8; ++ct)
            #pragma unroll
            for (int r = 0; r < 4; ++r) {
                int gr = rowbase + rt * 16 + q * 4 + r;
                outp[(size_t)gr * 128 + ct * 16 + m] = f2bf(acc[ct][r]);
            }
    }
}

// ---------------- gather aggregation: 16 lanes/node, 2-edge unroll, nt store ------
// out[n] = relu(bias + hw[n]*dinv[n]^2 + sum_s hw[s]*norm(s,n))
__global__ __launch_bounds__(256) void k_gather_bf(
    const unsigned short* __restrict__ hw, unsigned short* __restrict__ agg,
    const int* __restrict__ row_start, const int2* __restrict__ csr_ev,
    const float* __restrict__ dinv, const float* __restrict__ bias, int Nn)
{
    const int n  = blockIdx.x * 16 + (threadIdx.x >> 4);
    const int c8 = (threadIdx.x & 15) * 8;
    const float dv = dinv[n];
    const float d2 = dv * dv;

    float acc[8];
    {
        const short8 sv = *(const short8*)(hw + (size_t)n * HDIM + c8);
        #pragma unroll
        for (int j = 0; j < 8; ++j)
            acc[j] = fmaf(bf2f((unsigned short)sv[j]), d2, bias[c8 + j]);
    }

    const int s0 = row_start[n], s1 = row_start[n + 1];
    int i = s0;
    for (; i + 1 < s1; i += 2) {
        const int2 e0 = csr_ev[i];
        const int2 e1 = csr_ev[i + 1];
        const short8 r0 = *(const short8*)(hw + (size_t)e0.x * HDIM + c8);
        const short8 r1 = *(const short8*)(hw + (size_t)e1.x * HDIM + c8);
        const float w0 = __builtin_bit_cast(float, e0.y);
        const float w1 = __builtin_bit_cast(float, e1.y);
        #pragma unroll
        for (int j = 0; j < 8; ++j) acc[j] = fmaf(bf2f((unsigned short)r0[j]), w0, acc[j]);
        #pragma unroll
        for (int j = 0; j < 8; ++j) acc[j] = fmaf(bf2f((unsigned short)r1[j]), w1, acc[j]);
    }
    if (i < s1) {
        const int2 e0 = csr_ev[i];
        const short8 r0 = *(const short8*)(hw + (size_t)e0.x * HDIM + c8);
        const float w0 = __builtin_bit_cast(float, e0.y);
        #pragma unroll
        for (int j = 0; j < 8; ++j) acc[j] = fmaf(bf2f((unsigned short)r0[j]), w0, acc[j]);
    }

    short8 o;
    #pragma unroll
    for (int j = 0; j < 8; ++j) o[j] = f2bf(fmaxf(acc[j], 0.f));
    __builtin_nontemporal_store(o, (short8*)(agg + (size_t)n * HDIM + c8));
}

// ---------------- global max pool (rows already bias+relu'd), 256 thr/graph ------
__global__ __launch_bounds__(256) void k_pool(
    const unsigned short* __restrict__ agg,
    const int* __restrict__ batch, float* __restrict__ out, int Nn)
{
    __shared__ int se[2];
    __shared__ float red[256];
    int g = blockIdx.x;
    if (threadIdx.x < 2) {
        int target = g + (int)threadIdx.x;
        int lo = 0, hi = Nn;
        while (lo < hi) {
            int mid = (lo + hi) >> 1;
            if (batch[mid] < target) lo = mid + 1; else hi = mid;
        }
        se[threadIdx.x] = lo;
    }
    __syncthreads();
    const int start = se[0], end = se[1];
    const int c = threadIdx.x & 127;
    const int half = threadIdx.x >> 7;
    float m = 0.f;   // post-relu values >= 0; segments non-empty
    for (int i = start + half; i < end; i += 2)
        m = fmaxf(m, bf2f(__builtin_nontemporal_load(agg + (size_t)i * HDIM + c)));
    red[threadIdx.x] = m;
    __syncthreads();
    if (half == 0)
        out[(size_t)g * HDIM + c] = fmaxf(red[threadIdx.x], red[threadIdx.x + 128]);
}

// ---------------- f32 register-blocked GEMM (FF head only, tiny) ----------------
template<int K, int NC, bool OUT_RELU_BIAS>
__global__ __launch_bounds__(256) void k_gemm(
    const float* __restrict__ in, const float* __restrict__ W,
    const float* __restrict__ out_bias, float* __restrict__ out0, int M)
{
    constexpr int BK = 32;
    constexpr int TC = NC / 8;
    constexpr int TR = 256 / TC;
    constexpr int ROWS = TR * 8;
    constexpr int XST = ROWS + 4;

    __shared__ float xs[BK][XST];
    __shared__ float ws[BK][NC];

    const int tid = threadIdx.x;
    const int tc  = tid % TC;
    const int tr  = tid / TC;
    const int row0 = blockIdx.x * ROWS;

    float acc[8][8];
    #pragma unroll
    for (int i = 0; i < 8; ++i)
        #pragma unroll
        for (int j = 0; j < 8; ++j) acc[i][j] = 0.f;

    for (int k0 = 0; k0 < K; k0 += BK) {
        {
            constexpr int TASKS = BK * NC / 4;
            #pragma unroll
            for (int it = 0; it < TASKS / 256; ++it) {
                int t  = it * 256 + tid;
                int wk = t / (NC / 4);
                int wc = (t % (NC / 4)) * 4;
                *(float4*)(&ws[wk][wc]) = *(const float4*)(W + (size_t)(k0 + wk) * NC + wc);
            }
        }
        {
            constexpr int TASKS = ROWS * BK / 4;
            #pragma unroll
            for (int it = 0; it < TASKS / 256; ++it) {
                int t   = it * 256 + tid;
                int r   = t / (BK / 4);
                int kq  = (t % (BK / 4)) * 4;
                float4 x4 = *(const float4*)(in + (size_t)(row0 + r) * K + k0 + kq);
                xs[kq + 0][r] = x4.x; xs[kq + 1][r] = x4.y;
                xs[kq + 2][r] = x4.z; xs[kq + 3][r] = x4.w;
            }
        }
        __syncthreads();
        #pragma unroll 8
        for (int kk = 0; kk < BK; ++kk) {
            float a[8], b[8];
            #pragma unroll
            for (int i = 0; i < 8; ++i) a[i] = xs[kk][tr * 8 + i];
            #pragma unroll
            for (int j = 0; j < 8; ++j) b[j] = ws[kk][tc * 8 + j];
            #pragma unroll
            for (int i = 0; i < 8; ++i)
                #pragma unroll
                for (int j = 0; j < 8; ++j)
                    acc[i][j] = fmaf(a[i], b[j], acc[i][j]);
        }
        __syncthreads();
    }

    #pragma unroll
    for (int i = 0; i < 8; ++i) {
        const int row = row0 + tr * 8 + i;
        #pragma unroll
        for (int jq = 0; jq < 2; ++jq) {
            const int col = tc * 8 + jq * 4;
            float4 v;
            v.x = acc[i][jq * 4 + 0]; v.y = acc[i][jq * 4 + 1];
            v.z = acc[i][jq * 4 + 2]; v.w = acc[i][jq * 4 + 3];
            if constexpr (OUT_RELU_BIAS) {
                const float4 bb = *(const float4*)(out_bias + col);
                v.x = fmaxf(v.x + bb.x, 0.f); v.y = fmaxf(v.y + bb.y, 0.f);
                v.z = fmaxf(v.z + bb.z, 0.f); v.w = fmaxf(v.w + bb.w, 0.f);
            }
            *(float4*)(out0 + (size_t)row * NC + col) = v;
        }
    }
}

extern "C" void kernel_launch(void* const* d_in, const int* in_sizes, int n_in,
                              void* d_out, int out_size, void* d_ws, size_t ws_size,
                              hipStream_t stream) {
    const float* x    = (const float*)d_in[0];
    const int*   ei   = (const int*)d_in[1];
    const int*   batch= (const int*)d_in[2];
    const float* W0   = (const float*)d_in[3];
    const float* b0   = (const float*)d_in[4];
    const float* W1   = (const float*)d_in[5];
    const float* b1   = (const float*)d_in[6];
    const float* Wf0  = (const float*)d_in[7];
    const float* bf0  = (const float*)d_in[8];
    const float* Wf1  = (const float*)d_in[9];
    const float* bf1  = (const float*)d_in[10];
    float* out = (float*)d_out;

    const int* srcI = ei;
    const int* dstI = ei + NEDGES;

    constexpr int SCAN_NBLK = (NATOMS + 1023) / 1024;   // 391

    // workspace layout
    unsigned short* hwA  = (unsigned short*)d_ws;                 // N*128 bf16
    unsigned short* aggB = hwA + (size_t)NATOMS * HDIM;           // N*128 bf16
    float* dinv      = (float*)(aggB + (size_t)NATOMS * HDIM);    // N f32
    int*   row_start = (int*)(dinv + NATOMS);                     // N+1 (doubles as deg)
    int2*  csr_ev    = (int2*)(row_start + (NATOMS + 1) + 1);     // E (8B-aligned)
    int*   cursor    = (int*)(csr_ev + NEDGES);                   // N
    int*   blockSums = cursor + NATOMS;                           // 512
    float* pool      = (float*)(blockSums + 512);                 // G*128
    float* ff0       = pool + (size_t)NGRAPH * HDIM;              // G*256
    short* wf0       = (short*)(ff0 + (size_t)NGRAPH * FF0D);     // 8*3*64*8 bf16
    short* wf1       = wf0 + 8 * 3 * 64 * 8;                      // 8*4*64*8 bf16

    // 1) degree -> dinv ; CSR build (cursor seeded by scan3; no cursor memset)
    hipMemsetAsync(row_start, 0, (size_t)(NATOMS + 1) * sizeof(int), stream);
    k_degi<<<(NEDGES + 255) / 256, 256, 0, stream>>>(dstI, row_start, NEDGES);
    k_dinv<<<(NATOMS + 255) / 256, 256, 0, stream>>>(row_start, dinv, NATOMS);
    k_scan1<<<SCAN_NBLK, 256, 0, stream>>>(row_start, blockSums, NATOMS);
    k_scan2<<<1, 512, 0, stream>>>(blockSums, SCAN_NBLK);
    k_scan3<<<SCAN_NBLK, 256, 0, stream>>>(row_start, blockSums, cursor, NATOMS, NEDGES);
    k_fill<<<(NEDGES + 255) / 256, 256, 0, stream>>>(srcI, dstI, cursor, csr_ev, dinv, NEDGES);

    // 2) pack weights into MFMA B-fragment order (bf16)
    k_packw<3, F_INN><<<8 * 3, 64, 0, stream>>>(W0, wf0);
    k_packw<4, HDIM><<<8 * 4, 64, 0, stream>>>(W1, wf1);

    // 3) layer 0: hw0 = x@W0 (bf16) ; gather -> relu(agg + b0) bf16
    k_gemm_mfma<3, true, F_INN><<<1250, 256, 0, stream>>>(x, wf0, (short*)hwA, NATOMS);
    k_gather_bf<<<NATOMS / 16, 256, 0, stream>>>(hwA, aggB, row_start, csr_ev,
                                                 dinv, b0, NATOMS);

    // 4) layer 1: hw1 = h@W1 (bf16) ; gather -> relu(agg + b1) bf16
    k_gemm_mfma<4, false, HDIM><<<1250, 256, 0, stream>>>(aggB, wf1, (short*)hwA, NATOMS);
    k_gather_bf<<<NATOMS / 16, 256, 0, stream>>>(hwA, aggB, row_start, csr_ev,
                                                 dinv, b1, NATOMS);

    // 5) pool: segment max -> pool f32 [G,128]
    k_pool<<<NGRAPH, 256, 0, stream>>>(aggB, batch, pool, NATOMS);

    // 6) FF head (f32, tiny)
    k_gemm<HDIM, FF0D, true><<<NGRAPH / 64, 256, 0, stream>>>(pool, Wf0, bf0, ff0, NGRAPH);
    k_gemm<FF0D, FF1D, true><<<NGRAPH / 128, 256, 0, stream>>>(ff0, Wf1, bf1, out, NGRAPH);
}

// Round 6
// 753.290 us; speedup vs baseline: 8.0887x; 1.0348x over previous
//
#include <hip/hip_runtime.h>
#include <cstdint>
#include <cstddef>

// Problem constants (fixed by the reference)
#define NATOMS 400000
#define NEDGES 1600000
#define NGRAPH 4096
#define F_INN  78
#define HDIM   128
#define FF0D   256
#define FF1D   128

typedef __attribute__((ext_vector_type(8))) short short8;   // 8 bf16 (4 VGPRs)
typedef __attribute__((ext_vector_type(4))) float f32x4;
typedef __attribute__((ext_vector_type(2))) float f32x2;

// f32 -> bf16 round-to-nearest-even (bit-level)
static __device__ __forceinline__ short f2bf(float f) {
    unsigned u = __builtin_bit_cast(unsigned, f);
    unsigned r = (u + 0x7fffu + ((u >> 16) & 1u)) >> 16;
    return (short)r;
}
static __device__ __forceinline__ float bf2f(unsigned short u) {
    return __builtin_bit_cast(float, ((unsigned)u) << 16);
}

// ---------------- degree + per-edge rank (atomic return value) ----------------
__global__ __launch_bounds__(256) void k_degi(const int* __restrict__ dst,
                                              int* __restrict__ deg,
                                              int* __restrict__ rank, int E) {
    int e = blockIdx.x * 256 + threadIdx.x;
    if (e < E) rank[e] = atomicAdd(&deg[dst[e]], 1);
}

// ---------------- exclusive scan over N ints (3 kernels, in-place) ----------------
// scan1 also emits dinv = rsqrt(deg+1) (deg still intact at entry)
__global__ __launch_bounds__(256) void k_scan1(int* __restrict__ data,
                                               int* __restrict__ blockSums,
                                               float* __restrict__ dinv, int n) {
    __shared__ int ts[256];
    const int base = blockIdx.x * 1024 + threadIdx.x * 4;
    int v[4];
    #pragma unroll
    for (int j = 0; j < 4; ++j) v[j] = (base + j < n) ? data[base + j] : 0;
    #pragma unroll
    for (int j = 0; j < 4; ++j)
        if (base + j < n) dinv[base + j] = rsqrtf((float)v[j] + 1.0f);
    const int tot = v[0] + v[1] + v[2] + v[3];
    ts[threadIdx.x] = tot;
    __syncthreads();
    #pragma unroll
    for (int off = 1; off < 256; off <<= 1) {
        int t = (threadIdx.x >= off) ? ts[threadIdx.x - off] : 0;
        __syncthreads();
        ts[threadIdx.x] += t;
        __syncthreads();
    }
    int run = ts[threadIdx.x] - tot;
    #pragma unroll
    for (int j = 0; j < 4; ++j) {
        if (base + j < n) data[base + j] = run;
        run += v[j];
    }
    if (threadIdx.x == 255) blockSums[blockIdx.x] = ts[255];
}

__global__ __launch_bounds__(512) void k_scan2(int* __restrict__ blockSums, int nb) {
    __shared__ int ts[512];
    int v = (threadIdx.x < nb) ? blockSums[threadIdx.x] : 0;
    ts[threadIdx.x] = v;
    __syncthreads();
    #pragma unroll
    for (int off = 1; off < 512; off <<= 1) {
        int t = (threadIdx.x >= off) ? ts[threadIdx.x - off] : 0;
        __syncthreads();
        ts[threadIdx.x] += t;
        __syncthreads();
    }
    if (threadIdx.x < nb) blockSums[threadIdx.x] = ts[threadIdx.x] - v;
}

__global__ __launch_bounds__(256) void k_scan3(int* __restrict__ data,
                                               const int* __restrict__ blockSums,
                                               int n, int total) {
    const int off = blockSums[blockIdx.x];
    const int base = blockIdx.x * 1024 + threadIdx.x * 4;
    #pragma unroll
    for (int j = 0; j < 4; ++j)
        if (base + j < n) data[base + j] += off;
    if (blockIdx.x == 0 && threadIdx.x == 0) data[n] = total;
}

// ---------------- CSR fill: atomic-free (pos = row_start[d] + rank[e]) ----------
__global__ __launch_bounds__(256) void k_fill(const int* __restrict__ src,
                                              const int* __restrict__ dst,
                                              const int* __restrict__ row_start,
                                              const int* __restrict__ rank,
                                              int2* __restrict__ csr_ev,
                                              const float* __restrict__ dinv, int E) {
    int e = blockIdx.x * 256 + threadIdx.x;
    if (e >= E) return;
    int d = dst[e];
    int s = src[e];
    int pos = row_start[d] + rank[e];
    float norm = dinv[s] * dinv[d];
    csr_ev[pos] = make_int2(s, __builtin_bit_cast(int, norm));
}

// ---------------- weight pack: W [KSRC][128] f32 -> MFMA B-fragment order bf16 ----
template<int KC, int KSRC>
__global__ __launch_bounds__(64) void k_packw(const float* __restrict__ W,
                                              short* __restrict__ wf) {
    int t = blockIdx.x * 64 + threadIdx.x;      // t = f*64 + lane
    int f = t >> 6, lane = t & 63;
    int ct = f / KC, kc = f % KC;
    int n  = ct * 16 + (lane & 15);
    int k0 = kc * 32 + (lane >> 4) * 8;
    short8 o;
    #pragma unroll
    for (int j = 0; j < 8; ++j) {
        int k = k0 + j;
        float v = (k < KSRC) ? W[(size_t)k * 128 + n] : 0.f;
        o[j] = f2bf(v);
    }
    *(short8*)(wf + (size_t)t * 8) = o;
}

// ---------------- MFMA GEMM: out[M,128] = in[M,KSRC] @ W  (bf16 out) ----------------
// No LDS: B-fragments VGPR-resident, A straight from global (nt: streamed once).
// Output NOT nt: hw is re-read randomly by the gather — let it warm L2/L3.
template<int KC, bool F32IN, int KSRC>
__global__ __launch_bounds__(256) void k_gemm_mfma(
    const void* __restrict__ inv, const short* __restrict__ wfrag,
    short* __restrict__ outp, int M)
{
    constexpr int RT = 5;
    const int wid  = threadIdx.x >> 6;
    const int lane = threadIdx.x & 63;
    const int m = lane & 15, q = lane >> 4;
    const int rowbase = blockIdx.x * (4 * RT * 16) + wid * (RT * 16);

    short8 bfr[8 * KC];
    #pragma unroll
    for (int f = 0; f < 8 * KC; ++f)
        bfr[f] = *(const short8*)(wfrag + ((size_t)(f * 64 + lane)) * 8);

    for (int rt = 0; rt < RT; ++rt) {
        const int rowa = rowbase + rt * 16 + m;
        short8 afr[KC];
        if constexpr (F32IN) {
            const float* xr = (const float*)inv + (size_t)rowa * KSRC;
            #pragma unroll
            for (int kc = 0; kc < KC; ++kc) {
                const int k0 = kc * 32 + q * 8;
                float v[8];
                #pragma unroll
                for (int j = 0; j < 8; ++j) v[j] = 0.f;
                if (k0 < KSRC) {
                    #pragma unroll
                    for (int p = 0; p < 4; ++p) {
                        int k = k0 + 2 * p;
                        if (k < KSRC) {       // KSRC even: pairs never straddle
                            f32x2 t = __builtin_nontemporal_load((const f32x2*)(xr + k));
                            v[2 * p] = t.x; v[2 * p + 1] = t.y;
                        }
                    }
                }
                short8 a;
                #pragma unroll
                for (int j = 0; j < 8; ++j) a[j] = f2bf(v[j]);
                afr[kc] = a;
            }
        } else {
            const short* xr = (const short*)inv + (size_t)rowa * KSRC;
            #pragma unroll
            for (int kc = 0; kc < KC; ++kc)
                afr[kc] = __builtin_nontemporal_load((const short8*)(xr + kc * 32 + q * 8));
        }

        f32x4 acc[8];
        #pragma unroll
        for (int ct = 0; ct < 8; ++ct) acc[ct] = (f32x4){0.f, 0.f, 0.f, 0.f};
        #pragma unroll
        for (int kc = 0; kc < KC; ++kc)
            #pragma unroll
            for (int ct = 0; ct < 8; ++ct)
                acc[ct] = __builtin_amdgcn_mfma_f32_16x16x32_bf16(
                    afr[kc], bfr[ct * KC + kc], acc[ct], 0, 0, 0);

        // C layout: col = lane&15, row = q*4 + reg
        #pragma unroll
        for (int ct = 0; ct < 8; ++ct)
            #pragma unroll
            for (int r = 0; r < 4; ++r) {
                int gr = rowbase + rt * 16 + q * 4 + r;
                outp[(size_t)gr * 128 + ct * 16 + m] = f2bf(acc[ct][r]);
            }
    }
}

// ---------------- gather aggregation: 16 lanes/node, 2-edge unroll, nt store ------
// out[n] = relu(bias + hw[n]*dinv[n]^2 + sum_s hw[s]*norm(s,n))
__global__ __launch_bounds__(256) void k_gather_bf(
    const unsigned short* __restrict__ hw, unsigned short* __restrict__ agg,
    const int* __restrict__ row_start, const int2* __restrict__ csr_ev,
    const float* __restrict__ dinv, const float* __restrict__ bias, int Nn)
{
    const int n  = blockIdx.x * 16 + (threadIdx.x >> 4);
    const int c8 = (threadIdx.x & 15) * 8;
    const float dv = dinv[n];
    const float d2 = dv * dv;

    float acc[8];
    {
        const short8 sv = *(const short8*)(hw + (size_t)n * HDIM + c8);
        #pragma unroll
        for (int j = 0; j < 8; ++j)
            acc[j] = fmaf(bf2f((unsigned short)sv[j]), d2, bias[c8 + j]);
    }

    const int s0 = row_start[n], s1 = row_start[n + 1];
    int i = s0;
    for (; i + 1 < s1; i += 2) {
        const int2 e0 = csr_ev[i];
        const int2 e1 = csr_ev[i + 1];
        const short8 r0 = *(const short8*)(hw + (size_t)e0.x * HDIM + c8);
        const short8 r1 = *(const short8*)(hw + (size_t)e1.x * HDIM + c8);
        const float w0 = __builtin_bit_cast(float, e0.y);
        const float w1 = __builtin_bit_cast(float, e1.y);
        #pragma unroll
        for (int j = 0; j < 8; ++j) acc[j] = fmaf(bf2f((unsigned short)r0[j]), w0, acc[j]);
        #pragma unroll
        for (int j = 0; j < 8; ++j) acc[j] = fmaf(bf2f((unsigned short)r1[j]), w1, acc[j]);
    }
    if (i < s1) {
        const int2 e0 = csr_ev[i];
        const short8 r0 = *(const short8*)(hw + (size_t)e0.x * HDIM + c8);
        const float w0 = __builtin_bit_cast(float, e0.y);
        #pragma unroll
        for (int j = 0; j < 8; ++j) acc[j] = fmaf(bf2f((unsigned short)r0[j]), w0, acc[j]);
    }

    short8 o;
    #pragma unroll
    for (int j = 0; j < 8; ++j) o[j] = f2bf(fmaxf(acc[j], 0.f));
    __builtin_nontemporal_store(o, (short8*)(agg + (size_t)n * HDIM + c8));
}

// ---------------- global max pool (rows already bias+relu'd), 256 thr/graph ------
__global__ __launch_bounds__(256) void k_pool(
    const unsigned short* __restrict__ agg,
    const int* __restrict__ batch, float* __restrict__ out, int Nn)
{
    __shared__ int se[2];
    __shared__ float red[256];
    int g = blockIdx.x;
    if (threadIdx.x < 2) {
        int target = g + (int)threadIdx.x;
        int lo = 0, hi = Nn;
        while (lo < hi) {
            int mid = (lo + hi) >> 1;
            if (batch[mid] < target) lo = mid + 1; else hi = mid;
        }
        se[threadIdx.x] = lo;
    }
    __syncthreads();
    const int start = se[0], end = se[1];
    const int c = threadIdx.x & 127;
    const int half = threadIdx.x >> 7;
    float m = 0.f;   // post-relu values >= 0; segments non-empty
    for (int i = start + half; i < end; i += 2)
        m = fmaxf(m, bf2f(__builtin_nontemporal_load(agg + (size_t)i * HDIM + c)));
    red[threadIdx.x] = m;
    __syncthreads();
    if (half == 0)
        out[(size_t)g * HDIM + c] = fmaxf(red[threadIdx.x], red[threadIdx.x + 128]);
}

// ---------------- f32 register-blocked GEMM (FF head only, tiny) ----------------
template<int K, int NC, bool OUT_RELU_BIAS>
__global__ __launch_bounds__(256) void k_gemm(
    const float* __restrict__ in, const float* __restrict__ W,
    const float* __restrict__ out_bias, float* __restrict__ out0, int M)
{
    constexpr int BK = 32;
    constexpr int TC = NC / 8;
    constexpr int TR = 256 / TC;
    constexpr int ROWS = TR * 8;
    constexpr int XST = ROWS + 4;

    __shared__ float xs[BK][XST];
    __shared__ float ws[BK][NC];

    const int tid = threadIdx.x;
    const int tc  = tid % TC;
    const int tr  = tid / TC;
    const int row0 = blockIdx.x * ROWS;

    float acc[8][8];
    #pragma unroll
    for (int i = 0; i < 8; ++i)
        #pragma unroll
        for (int j = 0; j < 8; ++j) acc[i][j] = 0.f;

    for (int k0 = 0; k0 < K; k0 += BK) {
        {
            constexpr int TASKS = BK * NC / 4;
            #pragma unroll
            for (int it = 0; it < TASKS / 256; ++it) {
                int t  = it * 256 + tid;
                int wk = t / (NC / 4);
                int wc = (t % (NC / 4)) * 4;
                *(float4*)(&ws[wk][wc]) = *(const float4*)(W + (size_t)(k0 + wk) * NC + wc);
            }
        }
        {
            constexpr int TASKS = ROWS * BK / 4;
            #pragma unroll
            for (int it = 0; it < TASKS / 256; ++it) {
                int t   = it * 256 + tid;
                int r   = t / (BK / 4);
                int kq  = (t % (BK / 4)) * 4;
                float4 x4 = *(const float4*)(in + (size_t)(row0 + r) * K + k0 + kq);
                xs[kq + 0][r] = x4.x; xs[kq + 1][r] = x4.y;
                xs[kq + 2][r] = x4.z; xs[kq + 3][r] = x4.w;
            }
        }
        __syncthreads();
        #pragma unroll 8
        for (int kk = 0; kk < BK; ++kk) {
            float a[8], b[8];
            #pragma unroll
            for (int i = 0; i < 8; ++i) a[i] = xs[kk][tr * 8 + i];
            #pragma unroll
            for (int j = 0; j < 8; ++j) b[j] = ws[kk][tc * 8 + j];
            #pragma unroll
            for (int i = 0; i < 8; ++i)
                #pragma unroll
                for (int j = 0; j < 8; ++j)
                    acc[i][j] = fmaf(a[i], b[j], acc[i][j]);
        }
        __syncthreads();
    }

    #pragma unroll
    for (int i = 0; i < 8; ++i) {
        const int row = row0 + tr * 8 + i;
        #pragma unroll
        for (int jq = 0; jq < 2; ++jq) {
            const int col = tc * 8 + jq * 4;
            float4 v;
            v.x = acc[i][jq * 4 + 0]; v.y = acc[i][jq * 4 + 1];
            v.z = acc[i][jq * 4 + 2]; v.w = acc[i][jq * 4 + 3];
            if constexpr (OUT_RELU_BIAS) {
                const float4 bb = *(const float4*)(out_bias + col);
                v.x = fmaxf(v.x + bb.x, 0.f); v.y = fmaxf(v.y + bb.y, 0.f);
                v.z = fmaxf(v.z + bb.z, 0.f); v.w = fmaxf(v.w + bb.w, 0.f);
            }
            *(float4*)(out0 + (size_t)row * NC + col) = v;
        }
    }
}

extern "C" void kernel_launch(void* const* d_in, const int* in_sizes, int n_in,
                              void* d_out, int out_size, void* d_ws, size_t ws_size,
                              hipStream_t stream) {
    const float* x    = (const float*)d_in[0];
    const int*   ei   = (const int*)d_in[1];
    const int*   batch= (const int*)d_in[2];
    const float* W0   = (const float*)d_in[3];
    const float* b0   = (const float*)d_in[4];
    const float* W1   = (const float*)d_in[5];
    const float* b1   = (const float*)d_in[6];
    const float* Wf0  = (const float*)d_in[7];
    const float* bf0  = (const float*)d_in[8];
    const float* Wf1  = (const float*)d_in[9];
    const float* bf1  = (const float*)d_in[10];
    float* out = (float*)d_out;

    const int* srcI = ei;
    const int* dstI = ei + NEDGES;

    constexpr int SCAN_NBLK = (NATOMS + 1023) / 1024;   // 391

    // workspace layout — total ~227.2 MB, strictly below the round-4-proven 228.75 MB.
    // rank ALIASES the start of aggB: rank's lifetime (degi -> fill) ends before the
    // first gather writes aggB. All blocks 64B-aligned; pool/ff0 16B-aligned.
    char* base = (char*)d_ws;
    unsigned short* hwA  = (unsigned short*)(base + 0);              // N*128 bf16 = 102,400,000
    unsigned short* aggB = (unsigned short*)(base + 102400000);      // N*128 bf16 = 102,400,000
    int*   rank      = (int*)(base + 102400000);                     // E ints (alias of aggB)
    float* dinv      = (float*)(base + 204800000);                   // N f32 = 1,600,000
    int*   row_start = (int*)(base + 206400000);                     // N+1 ints
    int2*  csr_ev    = (int2*)(base + 208000064);                    // E int2 = 12,800,000
    int*   blockSums = (int*)(base + 220800064);                     // 512 ints
    float* pool      = (float*)(base + 220802112);                   // G*128 f32 = 2,097,152
    float* ff0       = (float*)(base + 222899264);                   // G*256 f32 = 4,194,304
    short* wf0       = (short*)(base + 227093568);                   // 8*3*64*8 bf16 = 24,576 B
    short* wf1       = (short*)(base + 227118144);                   // 8*4*64*8 bf16 = 32,768 B

    // 1) degree (+rank) -> scan (+dinv) -> atomic-free CSR fill
    hipMemsetAsync(row_start, 0, (size_t)(NATOMS + 1) * sizeof(int), stream);
    k_degi<<<(NEDGES + 255) / 256, 256, 0, stream>>>(dstI, row_start, rank, NEDGES);
    k_scan1<<<SCAN_NBLK, 256, 0, stream>>>(row_start, blockSums, dinv, NATOMS);
    k_scan2<<<1, 512, 0, stream>>>(blockSums, SCAN_NBLK);
    k_scan3<<<SCAN_NBLK, 256, 0, stream>>>(row_start, blockSums, NATOMS, NEDGES);
    k_fill<<<(NEDGES + 255) / 256, 256, 0, stream>>>(srcI, dstI, row_start, rank,
                                                     csr_ev, dinv, NEDGES);

    // 2) pack weights into MFMA B-fragment order (bf16)
    k_packw<3, F_INN><<<8 * 3, 64, 0, stream>>>(W0, wf0);
    k_packw<4, HDIM><<<8 * 4, 64, 0, stream>>>(W1, wf1);

    // 3) layer 0: hw0 = x@W0 (bf16) ; gather -> relu(agg + b0) bf16
    //    (first aggB write happens here — rank alias is dead by now)
    k_gemm_mfma<3, true, F_INN><<<1250, 256, 0, stream>>>(x, wf0, (short*)hwA, NATOMS);
    k_gather_bf<<<NATOMS / 16, 256, 0, stream>>>(hwA, aggB, row_start, csr_ev,
                                                 dinv, b0, NATOMS);

    // 4) layer 1: hw1 = h@W1 (bf16) ; gather -> relu(agg + b1) bf16
    k_gemm_mfma<4, false, HDIM><<<1250, 256, 0, stream>>>(aggB, wf1, (short*)hwA, NATOMS);
    k_gather_bf<<<NATOMS / 16, 256, 0, stream>>>(hwA, aggB, row_start, csr_ev,
                                                 dinv, b1, NATOMS);

    // 5) pool: segment max -> pool f32 [G,128]
    k_pool<<<NGRAPH, 256, 0, stream>>>(aggB, batch, pool, NATOMS);

    // 6) FF head (f32, tiny)
    k_gemm<HDIM, FF0D, true><<<NGRAPH / 64, 256, 0, stream>>>(pool, Wf0, bf0, ff0, NGRAPH);
    k_gemm<FF0D, FF1D, true><<<NGRAPH / 128, 256, 0, stream>>>(ff0, Wf1, bf1, out, NGRAPH);
}